// Round 1
// baseline (58.727 us; speedup 1.0000x reference)
//
#include <hip/hip_runtime.h>

// Problem constants (match reference SIZE/BATCH/CHANNELS)
#define DD 128
#define HH 160
#define WW 128
#define BB 4
#define DHW (DD * HH * WW)

__global__ __launch_bounds__(256)
void st_affine_kernel(const float* __restrict__ src,
                      const float* __restrict__ aff,
                      float* __restrict__ out,
                      int total) {
    int idx = blockIdx.x * blockDim.x + threadIdx.x;
    if (idx >= total) return;

    int b  = idx / DHW;
    int r  = idx - b * DHW;
    int z  = r / (HH * WW);
    int r2 = r - z * (HH * WW);
    int y  = r2 / WW;
    int x  = r2 - y * WW;

    const float* A = aff + b * 12;
    float fz = (float)z, fy = (float)y, fx = (float)x;

    // loc = A @ [z, y, x, 1]
    float lz = A[0] * fz + A[1] * fy + A[2]  * fx + A[3];
    float ly = A[4] * fz + A[5] * fy + A[6]  * fx + A[7];
    float lx = A[8] * fz + A[9] * fy + A[10] * fx + A[11];

    // mirror reference arithmetic order exactly:
    // g = 2*(loc/(size-1) - 0.5);  i = ((g+1)*size - 1)*0.5
    float gz = 2.0f * (lz / (float)(DD - 1) - 0.5f);
    float gy = 2.0f * (ly / (float)(HH - 1) - 0.5f);
    float gx = 2.0f * (lx / (float)(WW - 1) - 0.5f);
    float ix = ((gx + 1.0f) * (float)WW - 1.0f) * 0.5f;
    float iy = ((gy + 1.0f) * (float)HH - 1.0f) * 0.5f;
    float iz = ((gz + 1.0f) * (float)DD - 1.0f) * 0.5f;

    // border clamp
    ix = fminf(fmaxf(ix, 0.0f), (float)(WW - 1));
    iy = fminf(fmaxf(iy, 0.0f), (float)(HH - 1));
    iz = fminf(fmaxf(iz, 0.0f), (float)(DD - 1));

    float x0f = floorf(ix), y0f = floorf(iy), z0f = floorf(iz);
    float wx = ix - x0f, wy = iy - y0f, wz = iz - z0f;

    int x0 = (int)x0f, y0 = (int)y0f, z0 = (int)z0f;
    int x1 = min(x0 + 1, WW - 1);
    int y1 = min(y0 + 1, HH - 1);
    int z1 = min(z0 + 1, DD - 1);

    const float* s = src + b * DHW;
    int zy00 = (z0 * HH + y0) * WW;
    int zy01 = (z0 * HH + y1) * WW;
    int zy10 = (z1 * HH + y0) * WW;
    int zy11 = (z1 * HH + y1) * WW;

    float c000 = s[zy00 + x0], c001 = s[zy00 + x1];
    float c010 = s[zy01 + x0], c011 = s[zy01 + x1];
    float c100 = s[zy10 + x0], c101 = s[zy10 + x1];
    float c110 = s[zy11 + x0], c111 = s[zy11 + x1];

    float c00 = c000 + (c001 - c000) * wx;
    float c01 = c010 + (c011 - c010) * wx;
    float c10 = c100 + (c101 - c100) * wx;
    float c11 = c110 + (c111 - c110) * wx;
    float c0  = c00 + (c01 - c00) * wy;
    float c1  = c10 + (c11 - c10) * wy;
    out[idx]  = c0 + (c1 - c0) * wz;
}

extern "C" void kernel_launch(void* const* d_in, const int* in_sizes, int n_in,
                              void* d_out, int out_size, void* d_ws, size_t ws_size,
                              hipStream_t stream) {
    const float* src = (const float*)d_in[0];
    const float* aff = (const float*)d_in[1];
    float* out = (float*)d_out;

    int total = BB * DHW;  // == out_size
    int block = 256;
    int grid  = (total + block - 1) / block;
    st_affine_kernel<<<grid, block, 0, stream>>>(src, aff, out, total);
}